// Round 2
// baseline (9.855 us; speedup 1.0000x reference)
//
#include <hip/hip_runtime.h>

// HBV hydrological step, LDS-staged + vectorized version.
// One thread per basin, 256 basins per block.
// Inputs: y (B,5) f32, theta (B,13) f32, climate_data (T,B,3) f32, t (1,) i32.
// Output: dS (B,5) f32 flattened, then fluxes (B,) f32.

#define TPB 256

__global__ __launch_bounds__(TPB) void hbv_step_kernel(
    const float* __restrict__ y,
    const float* __restrict__ theta,
    const float* __restrict__ clim,
    const int* __restrict__ tptr,
    float* __restrict__ out,
    int B)
{
    __shared__ float sy [TPB * 5];
    __shared__ float sth[TPB * 13];
    __shared__ float sc [TPB * 3];
    __shared__ float sdS[TPB * 5];
    __shared__ float sfx[TPB];

    const int tid = threadIdx.x;
    const int blk = blockIdx.x;
    const int b0  = blk * TPB;
    const int nb  = min(TPB, B - b0);       // basins handled by this block
    const int t   = tptr[0];
    const size_t cbase = ((size_t)t * (size_t)B + (size_t)b0) * 3;

    if (nb == TPB) {
        // Full tile: float4 coalesced staging (tile byte offsets are 16B-aligned:
        // y tile = 1280 floats, theta tile = 3328 floats per block).
        const float4* y4  = (const float4*)y     + (size_t)blk * (TPB * 5 / 4);
        const float4* th4 = (const float4*)theta + (size_t)blk * (TPB * 13 / 4);
        float4* sy4  = (float4*)sy;
        float4* sth4 = (float4*)sth;
        #pragma unroll
        for (int i = tid; i < TPB * 5 / 4; i += TPB)  sy4[i]  = y4[i];
        #pragma unroll
        for (int i = tid; i < TPB * 13 / 4; i += TPB) sth4[i] = th4[i];
        #pragma unroll
        for (int i = tid; i < TPB * 3; i += TPB)      sc[i]   = clim[cbase + i];
    } else {
        // Tail tile: guarded scalar coalesced staging.
        for (int i = tid; i < nb * 5; i += TPB)  sy[i]  = y[(size_t)b0 * 5 + i];
        for (int i = tid; i < nb * 13; i += TPB) sth[i] = theta[(size_t)b0 * 13 + i];
        for (int i = tid; i < nb * 3; i += TPB)  sc[i]  = clim[cbase + i];
    }
    __syncthreads();

    if (tid < nb) {
        // LDS reads: strides 5/13/3 are coprime with 32 banks -> conflict-free
        // (the lane/lane+32 2-way alias is free on CDNA4).
        const float* th = sth + tid * 13;
        const float* yr = sy + tid * 5;
        const float* cr = sc + tid * 3;

        const float parBETA   = 1.0f   + th[0]  * 5.0f;
        const float parFC     = 50.0f  + th[1]  * 950.0f;
        const float parK0     = 0.05f  + th[2]  * 0.85f;
        const float parK1     = 0.01f  + th[3]  * 0.49f;
        const float parK2     = 0.001f + th[4]  * 0.199f;
        const float parLP     = 0.2f   + th[5]  * 0.8f;
        const float parPERC   =          th[6]  * 10.0f;
        const float parUZL    =          th[7]  * 100.0f;
        const float parTT     = -2.5f  + th[8]  * 5.0f;
        const float parCFMAX  = 0.5f   + th[9]  * 9.5f;
        const float parCFR    =          th[10] * 0.1f;
        const float parCWH    =          th[11] * 0.2f;
        const float parBETAET = 0.3f   + th[12] * 4.7f;

        const float SNOWPACK  = fmaxf(yr[0], 0.0f);
        const float MELTWATER = fmaxf(yr[1], 0.0f);
        const float SM        = fmaxf(yr[2], 1e-8f);
        const float SUZ       = fmaxf(yr[3], 0.0f);
        const float SLZ       = fmaxf(yr[4], 0.0f);

        const float P  = cr[0];
        const float T_ = cr[1];
        const float Ep = cr[2];

        const float flux_sf    = (T_ < parTT) ? P : 0.0f;
        const float flux_refr  = fminf(fmaxf(parCFR * parCFMAX * (parTT - T_), 0.0f), MELTWATER);
        const float flux_melt  = fminf(fmaxf(parCFMAX * (T_ - parTT), 0.0f), SNOWPACK);
        const float flux_rf    = (T_ >= parTT) ? P : 0.0f;
        const float flux_Isnow = fmaxf(MELTWATER - parCWH * SNOWPACK, 0.0f);

        // SM >= 1e-8, FC >= 50, LP >= 0.2 -> strictly positive bases; fast pow ok.
        const float soil_wetness = fminf(__powf(SM / parFC, parBETA), 1.0f);
        const float flux_PEFF  = (flux_rf + flux_Isnow) * soil_wetness;
        const float flux_ex    = fmaxf(SM - parFC, 0.0f);
        const float evapfactor = fminf(__powf(SM / (parLP * parFC), parBETAET), 1.0f);
        const float flux_et    = fminf(SM, Ep * evapfactor);

        const float flux_perc  = fminf(SUZ, parPERC);
        const float flux_q0    = parK0 * fmaxf(SUZ - parUZL, 0.0f);
        const float flux_q1    = parK1 * SUZ;
        const float flux_q2    = parK2 * SLZ;

        float* d = sdS + tid * 5;
        d[0] = flux_sf + flux_refr - flux_melt;
        d[1] = flux_melt - flux_refr - flux_Isnow;
        d[2] = flux_Isnow + flux_rf - flux_PEFF - flux_ex - flux_et;
        d[3] = flux_PEFF + flux_ex - flux_perc - flux_q0 - flux_q1;
        d[4] = flux_perc - flux_q2;
        sfx[tid] = flux_q0 + flux_q1 + flux_q2;
    }
    __syncthreads();

    if (nb == TPB) {
        float4* o4 = (float4*)out + (size_t)blk * (TPB * 5 / 4);
        const float4* s4 = (const float4*)sdS;
        #pragma unroll
        for (int i = tid; i < TPB * 5 / 4; i += TPB) o4[i] = s4[i];
        out[(size_t)B * 5 + b0 + tid] = sfx[tid];
    } else {
        for (int i = tid; i < nb * 5; i += TPB) out[(size_t)b0 * 5 + i] = sdS[i];
        if (tid < nb) out[(size_t)B * 5 + b0 + tid] = sfx[tid];
    }
}

extern "C" void kernel_launch(void* const* d_in, const int* in_sizes, int n_in,
                              void* d_out, int out_size, void* d_ws, size_t ws_size,
                              hipStream_t stream) {
    const float* y     = (const float*)d_in[0];
    const float* theta = (const float*)d_in[1];
    const float* clim  = (const float*)d_in[2];
    const int*   tptr  = (const int*)d_in[3];
    float* out = (float*)d_out;

    const int B = in_sizes[0] / 5;  // y is (B,5)

    const int grid = (B + TPB - 1) / TPB;
    hbv_step_kernel<<<grid, TPB, 0, stream>>>(y, theta, clim, tptr, out, B);
}